// Round 10
// baseline (105.110 us; speedup 1.0000x reference)
//
#include <hip/hip_runtime.h>
#include <cstdint>

// BasisFunction1D: out[o,b] = sum_i (1-d)*P[idx,o,i] + d*P[idx+1,o,i]
//
// R9: DS-pipe-bound LDS path, tuned: PH=16 (7 barriers, 2x drain amortization),
//   phase-PAIR bodies so slab buffer select is a compile-time ds_read immediate
//   (only v_and + v_and_or per iter), ping-pong T prefetch regs, DMA staging.
//   512 thr = 8 waves, 512 b x 4 o per block, grid 512 = 2 blocks/CU,
//   LDS 64 KB/block (2x32 KB slab buffers).
//   Q2[s][i][g][ow]: per-(s,i) slab = 2 KB contiguous. T[i][b]=(idx<<4)|(d_h<<16).

#define NG 128
#define NI 128
#define NO 128
#define NB 8192
#define WO 4
#define PH 16
#define NPH (NI / PH)               // 8 phases, processed as 4 pairs
#define BT 512
#define PHW (PH * NG * WO)          // u32 per phase slab (8192 = 32 KB)

using half2v = __attribute__((ext_vector_type(2))) _Float16;

__device__ inline uint32_t pack_f16x2(float lo, float hi) {
    _Float16 hl = (_Float16)lo, hh = (_Float16)hi;
    return (uint32_t)__builtin_bit_cast(unsigned short, hl) |
           ((uint32_t)__builtin_bit_cast(unsigned short, hh) << 16);
}

// ---- K1: P[g,o,i] -> Q2[((s*NI+i)*NG+g)*4+ow] = pack(P, dP), o=s*4+ow ----
__global__ __launch_bounds__(256) void build_q(const float* __restrict__ P,
                                               uint32_t* __restrict__ Q2) {
    __shared__ float lp[32][129];
    __shared__ float ln[32][129];
    const int g  = blockIdx.x >> 2;
    const int o0 = (blockIdx.x & 3) * 32;
    const int t  = threadIdx.x;
    #pragma unroll
    for (int p = 0; p < 16; ++p) {
        int e = p * 256 + t;
        int ol = e >> 7, i = e & 127;
        lp[ol][i] = P[(size_t)(g * NO + o0 + ol) * NI + i];
        ln[ol][i] = P[(size_t)((g + 1) * NO + o0 + ol) * NI + i];
    }
    __syncthreads();
    #pragma unroll
    for (int p = 0; p < 4; ++p) {
        int e = p * 256 + t;          // 8 s_loc x 128 i
        int sl = e >> 7, i = e & 127;
        uint32_t r[4];
        #pragma unroll
        for (int ow = 0; ow < 4; ++ow) {
            float pl = lp[sl * 4 + ow][i];
            float dd = ln[sl * 4 + ow][i] - pl;
            r[ow] = pack_f16x2(pl, dd);
        }
        int s = (o0 >> 2) + sl;
        *(uint4*)(Q2 + ((size_t)(s * NI + i) * NG + g) * 4) =
            make_uint4(r[0], r[1], r[2], r[3]);
    }
}

// ---- K2: bucketize x -> T[i][b] = (idx*16) | (f16(d) << 16) ----
__global__ __launch_bounds__(256) void build_t(const float* __restrict__ x,
                                               const float* __restrict__ borders,
                                               const float* __restrict__ icl,
                                               uint32_t* __restrict__ T) {
    const int e0 = (blockIdx.x * 256 + threadIdx.x) * 4;
    const float4 xv = *(const float4*)(x + e0);
    uint32_t r[4];
    const float xs[4] = {xv.x, xv.y, xv.z, xv.w};
    #pragma unroll
    for (int k = 0; k < 4; ++k) {
        float v = xs[k];
        float ea = __expf(-fabsf(v));
        float cdf = v > 0.f ? 1.f - 0.5f * ea : 0.5f * ea;
        int idx = (int)(cdf * 128.f);
        idx = idx > 127 ? 127 : idx;
        float d = (v - borders[idx]) * icl[idx];
        _Float16 hd = (_Float16)d;
        r[k] = ((uint32_t)idx << 4) |
               ((uint32_t)__builtin_bit_cast(unsigned short, hd) << 16);
    }
    *(uint4*)(T + e0) = make_uint4(r[0], r[1], r[2], r[3]);
}

#define STAGE(srcp, dstp)                                                     \
    {                                                                         \
        const uint32_t* _s = (srcp);                                          \
        uint32_t* _d = (dstp);                                                \
        _Pragma("unroll")                                                     \
        for (int c = 0; c < 4; ++c)                                           \
            __builtin_amdgcn_global_load_lds(                                 \
                (const __attribute__((address_space(1))) uint32_t*)           \
                    (_s + c * 2048 + (size_t)t * 4),                          \
                (__attribute__((address_space(3))) uint32_t*)                 \
                    (_d + c * 2048 + (size_t)t * 4),                          \
                16, 0, 0);                                                    \
    }

#define COMPUTE(bufc, tarr)                                                   \
    _Pragma("unroll")                                                         \
    for (int il = 0; il < PH; ++il) {                                         \
        uint32_t tw  = (tarr)[il];                                            \
        uint32_t off = tw & 0x7F0u;                                           \
        uint32_t w2b = (tw & 0xFFFF0000u) | 0x3C00u;                          \
        uint4 q = *(const uint4*)((const char*)&slab[bufc][il][0] + off);     \
        half2v w2 = __builtin_bit_cast(half2v, w2b);                          \
        a0 = __builtin_amdgcn_fdot2(__builtin_bit_cast(half2v, q.x), w2, a0, false); \
        a1 = __builtin_amdgcn_fdot2(__builtin_bit_cast(half2v, q.y), w2, a1, false); \
        a2 = __builtin_amdgcn_fdot2(__builtin_bit_cast(half2v, q.z), w2, a2, false); \
        a3 = __builtin_amdgcn_fdot2(__builtin_bit_cast(half2v, q.w), w2, a3, false); \
    }

#define TLOAD(tarr, ph)                                                       \
    _Pragma("unroll")                                                         \
    for (int il = 0; il < PH; ++il)                                           \
        (tarr)[il] = Tb[(size_t)((ph) * PH + il) * NB];

// ---- K3: main. 512 thr; 512 b x 4 o; PH=16 phase-pairs, 7 barriers ----
__global__ __launch_bounds__(512) void main_k(const uint32_t* __restrict__ Q2,
                                              const uint32_t* __restrict__ T,
                                              float* __restrict__ out) {
    __shared__ uint32_t slab[2][PH][NG * WO];   // 2 x 32 KB
    const int t    = threadIdx.x;
    const int bx   = blockIdx.x;
    const int s    = bx & 31;                   // o-slice (4 o)
    const int bblk = (bx >> 5) * BT;            // b-tile of 512
    const int bme  = bblk + t;
    const uint32_t* Qs = Q2 + (size_t)s * NI * NG * WO;
    const uint32_t* Tb = T + bme;

    float a0 = 0.f, a1 = 0.f, a2 = 0.f, a3 = 0.f;
    uint32_t tA[PH], tB[PH];

    // prologue: stage phase 0 -> buf0; T phase 0 -> tA
    STAGE(Qs, &slab[0][0][0]);
    TLOAD(tA, 0);
    __syncthreads();

    #pragma unroll 1
    for (int pp = 0; pp < NPH / 2; ++pp) {
        const int pe = 2 * pp;                  // even phase (buf0, tA)
        // stage phase pe+1 -> buf1; prefetch T -> tB; compute buf0/tA
        STAGE(Qs + (size_t)(pe + 1) * PHW, &slab[1][0][0]);
        TLOAD(tB, pe + 1);
        COMPUTE(0, tA);
        __syncthreads();                        // buf1 DMA + tB drained

        // odd phase (buf1, tB): stage pe+2 -> buf0 unless last pair
        if (pp < NPH / 2 - 1) {
            STAGE(Qs + (size_t)(pe + 2) * PHW, &slab[0][0][0]);
            TLOAD(tA, pe + 2);
        }
        COMPUTE(1, tB);
        if (pp < NPH / 2 - 1) __syncthreads();
    }

    // epilogue: o = s*4 + {0..3}; 512-lane contiguous run per o
    size_t ob = (size_t)(s * 4) * NB + bme;
    __builtin_nontemporal_store(a0, out + ob);
    __builtin_nontemporal_store(a1, out + ob + NB);
    __builtin_nontemporal_store(a2, out + ob + 2 * (size_t)NB);
    __builtin_nontemporal_store(a3, out + ob + 3 * (size_t)NB);
}

extern "C" void kernel_launch(void* const* d_in, const int* in_sizes, int n_in,
                              void* d_out, int out_size, void* d_ws, size_t ws_size,
                              hipStream_t stream) {
    const float* x       = (const float*)d_in[0];
    const float* P       = (const float*)d_in[1];
    const float* borders = (const float*)d_in[2];
    const float* icl     = (const float*)d_in[3];
    float* out = (float*)d_out;

    uint32_t* Q2 = (uint32_t*)d_ws;                 // 8.4 MB
    uint32_t* T  = Q2 + (size_t)NO * NI * NG;       // 4.2 MB

    hipLaunchKernelGGL(build_q, dim3(NG * 4), dim3(256), 0, stream, P, Q2);
    hipLaunchKernelGGL(build_t, dim3(NI * NB / 1024), dim3(256), 0, stream,
                       x, borders, icl, T);
    hipLaunchKernelGGL(main_k, dim3((NB / BT) * 32), dim3(BT), 0, stream,
                       Q2, T, out);
}

// Round 11
// 102.495 us; speedup vs baseline: 1.0255x; 1.0255x over previous
//
#include <hip/hip_runtime.h>
#include <cstdint>

// BasisFunction1D: out[o,b] = sum_i (1-d)*P[idx,o,i] + d*P[idx+1,o,i]
//
// R10 = R6 skeleton (best: 93.7 us) with zero-VALU inner addressing:
//   Q2[s][i][g][ow] = pack_f16{ P[g,o,i], P[g+1,o,i] }   (8.4 MB; o = s*4+ow)
//   T2[i][b] = u64 { lo32 = idx*16 (ready LDS byte offset, hi bits 0),
//                    hi32 = f16x2 {1-d, d} (ready fdot2 weight) }  (8.4 MB)
//   main: 1024 thr = 16 waves, 1024 b x 4 o per block, grid 256 (1 blk/CU).
//     16 phases x 8 i, double-buffered 2x16 KB LDS, reg staging (dwordx4 at
//     top of phase, ds_write before barrier), T2 prefetched one phase ahead.
//     Inner il: ds_read_b128 (vaddr = T2.lo reg) + 4 fdot2. No mask ops.

#define NG 128
#define NI 128
#define NO 128
#define NB 8192
#define WO 4
#define PH 8
#define NPH (NI / PH)
#define PHW (PH * NG * WO)          // u32 per phase slab (4096 = 16 KB)

using half2v = __attribute__((ext_vector_type(2))) _Float16;

__device__ inline uint32_t pack_f16x2(float lo, float hi) {
    _Float16 hl = (_Float16)lo, hh = (_Float16)hi;
    return (uint32_t)__builtin_bit_cast(unsigned short, hl) |
           ((uint32_t)__builtin_bit_cast(unsigned short, hh) << 16);
}

// ---- K1 (fused): blocks [0,512): build Q2; blocks [512,1536): build T2 ----
__global__ __launch_bounds__(256) void build_qt(const float* __restrict__ P,
                                                const float* __restrict__ x,
                                                const float* __restrict__ borders,
                                                const float* __restrict__ icl,
                                                uint32_t* __restrict__ Q2,
                                                uint2* __restrict__ T2) {
    const int bx = blockIdx.x;
    const int t  = threadIdx.x;
    if (bx < 512) {
        // ---- Q part: P[g,o,i] -> Q2[((s*NI+i)*NG+g)*4+ow] = {P_l, P_r} ----
        __shared__ float lp[32][129];
        __shared__ float ln[32][129];
        const int g  = bx >> 2;
        const int o0 = (bx & 3) * 32;
        #pragma unroll
        for (int p = 0; p < 16; ++p) {
            int e = p * 256 + t;
            int ol = e >> 7, i = e & 127;
            lp[ol][i] = P[(size_t)(g * NO + o0 + ol) * NI + i];
            ln[ol][i] = P[(size_t)((g + 1) * NO + o0 + ol) * NI + i];
        }
        __syncthreads();
        #pragma unroll
        for (int p = 0; p < 4; ++p) {
            int e = p * 256 + t;          // 8 s_loc x 128 i
            int sl = e >> 7, i = e & 127;
            uint32_t r[4];
            #pragma unroll
            for (int ow = 0; ow < 4; ++ow)
                r[ow] = pack_f16x2(lp[sl * 4 + ow][i], ln[sl * 4 + ow][i]);
            int s = (o0 >> 2) + sl;
            *(uint4*)(Q2 + ((size_t)(s * NI + i) * NG + g) * 4) =
                make_uint4(r[0], r[1], r[2], r[3]);
        }
    } else {
        // ---- T part: x -> T2[i][b] = { idx*16, f16x2{1-d, d} } ----
        const int e0 = ((bx - 512) * 256 + t) * 4;
        const float4 xv = *(const float4*)(x + e0);
        uint2 r[4];
        const float xs[4] = {xv.x, xv.y, xv.z, xv.w};
        #pragma unroll
        for (int k = 0; k < 4; ++k) {
            float v = xs[k];
            float ea = __expf(-fabsf(v));
            float cdf = v > 0.f ? 1.f - 0.5f * ea : 0.5f * ea;
            int idx = (int)(cdf * 128.f);
            idx = idx > 127 ? 127 : idx;
            float d = (v - borders[idx]) * icl[idx];
            r[k].x = (uint32_t)idx << 4;
            r[k].y = pack_f16x2(1.f - d, d);
        }
        *(uint4*)(T2 + e0)     = make_uint4(r[0].x, r[0].y, r[1].x, r[1].y);
        *(uint4*)(T2 + e0 + 2) = make_uint4(r[2].x, r[2].y, r[3].x, r[3].y);
    }
}

// ---- K2: main. 1024 thr; 1024 b x 4 o; reg staging; zero-VALU inner ----
__global__ __launch_bounds__(1024) void main_k(const uint32_t* __restrict__ Q2,
                                               const uint2* __restrict__ T2,
                                               float* __restrict__ out) {
    __shared__ uint32_t slab[2][PH][NG * WO];   // 2 x 16 KB
    const int t    = threadIdx.x;
    const int bx   = blockIdx.x;
    const int s    = bx & 31;                   // o-slice (4 o)
    const int bblk = (bx >> 5) << 10;           // b-tile of 1024
    const int bme  = bblk + t;
    const uint32_t* Qs = Q2 + (size_t)s * NI * NG * WO;
    const uint2* Tb = T2 + bme;

    float a0 = 0.f, a1 = 0.f, a2 = 0.f, a3 = 0.f;
    uint2 tc[PH];

    // prologue: stage phase 0; T2 phase 0 -> tc
    {
        uint4 q0 = *(const uint4*)(Qs + (size_t)t * 4);
        #pragma unroll
        for (int il = 0; il < PH; ++il)
            tc[il] = Tb[(size_t)il * NB];
        ((uint4*)&slab[0][0][0])[t] = q0;
    }
    __syncthreads();

    #pragma unroll 1
    for (int p = 0; p < NPH; ++p) {
        const int cur = p & 1;
        uint2 tn[PH];
        uint4 qn;
        if (p < NPH - 1) {
            qn = *(const uint4*)(Qs + (size_t)(p + 1) * PHW + (size_t)t * 4);
            #pragma unroll
            for (int il = 0; il < PH; ++il)
                tn[il] = Tb[(size_t)((p + 1) * PH + il) * NB];
        }
        #pragma unroll
        for (int il = 0; il < PH; ++il) {
            uint2 tv = tc[il];
            // vaddr comes straight from the loaded reg; no mask/shift ops
            uint4 q = *(const uint4*)((const char*)&slab[cur][il][0] + tv.x);
            half2v w2 = __builtin_bit_cast(half2v, tv.y);   // {1-d, d}
            a0 = __builtin_amdgcn_fdot2(__builtin_bit_cast(half2v, q.x), w2, a0, false);
            a1 = __builtin_amdgcn_fdot2(__builtin_bit_cast(half2v, q.y), w2, a1, false);
            a2 = __builtin_amdgcn_fdot2(__builtin_bit_cast(half2v, q.z), w2, a2, false);
            a3 = __builtin_amdgcn_fdot2(__builtin_bit_cast(half2v, q.w), w2, a3, false);
        }
        if (p < NPH - 1) {
            ((uint4*)&slab[cur ^ 1][0][0])[t] = qn;
            #pragma unroll
            for (int il = 0; il < PH; ++il)
                tc[il] = tn[il];
            __syncthreads();
        }
    }

    // epilogue: o = s*4 + {0..3}; 1024-lane contiguous run per o
    size_t ob = (size_t)(s * 4) * NB + bme;
    __builtin_nontemporal_store(a0, out + ob);
    __builtin_nontemporal_store(a1, out + ob + NB);
    __builtin_nontemporal_store(a2, out + ob + 2 * (size_t)NB);
    __builtin_nontemporal_store(a3, out + ob + 3 * (size_t)NB);
}

extern "C" void kernel_launch(void* const* d_in, const int* in_sizes, int n_in,
                              void* d_out, int out_size, void* d_ws, size_t ws_size,
                              hipStream_t stream) {
    const float* x       = (const float*)d_in[0];
    const float* P       = (const float*)d_in[1];
    const float* borders = (const float*)d_in[2];
    const float* icl     = (const float*)d_in[3];
    float* out = (float*)d_out;

    uint32_t* Q2 = (uint32_t*)d_ws;                 // 8.4 MB
    uint2*    T2 = (uint2*)(Q2 + (size_t)NO * NI * NG);   // 8.4 MB

    hipLaunchKernelGGL(build_qt, dim3(512 + NI * NB / 1024), dim3(256), 0,
                       stream, P, x, borders, icl, Q2, T2);
    hipLaunchKernelGGL(main_k, dim3((NB / 1024) * 32), dim3(1024), 0, stream,
                       Q2, T2, out);
}